// Round 3
// baseline (120.732 us; speedup 1.0000x reference)
//
#include <hip/hip_runtime.h>
#include <hip/hip_bf16.h>

#define B_ROWS 4096
#define N2 8192
#define DD 512
#define NBT 32          // 8192/256 tile-blocks per dim
#define NTRI 528        // NBT*(NBT+1)/2
#define NT 8            // DD/64 K-tiles

typedef __attribute__((ext_vector_type(8))) short short8v;
typedef __attribute__((ext_vector_type(4))) float float4v;

__device__ inline unsigned int f2bf(float f) {
  unsigned int u = __float_as_uint(f);
  u += 0x7fffu + ((u >> 16) & 1u);
  return u >> 16;
}

#define BAR() do { asm volatile("" ::: "memory"); __builtin_amdgcn_s_barrier(); asm volatile("" ::: "memory"); } while (0)

// ---------- normalize + target fused: one wave per row, pairs share a block ----------
__global__ __launch_bounds__(256) void k_norm_tgt(const float* __restrict__ f1,
                                                  const float* __restrict__ f2,
                                                  uint4* __restrict__ zn,
                                                  float* __restrict__ tpart) {
  __shared__ float z2s[2][DD];
  int w = threadIdx.x >> 6, lane = threadIdx.x & 63;
  int jj = blockIdx.x * 2 + (w & 1);
  bool side2 = (w >= 2);
  int row = side2 ? (B_ROWS + jj) : jj;
  const float* src = (side2 ? f2 : f1) + (size_t)jj * DD;
  float4 v0 = ((const float4*)src)[lane * 2];
  float4 v1 = ((const float4*)src)[lane * 2 + 1];
  float ss = v0.x * v0.x + v0.y * v0.y + v0.z * v0.z + v0.w * v0.w +
             v1.x * v1.x + v1.y * v1.y + v1.z * v1.z + v1.w * v1.w;
#pragma unroll
  for (int o = 1; o < 64; o <<= 1) ss += __shfl_xor(ss, o, 64);
  float inv = 1.0f / fmaxf(sqrtf(ss), 1e-8f);
  float s0 = v0.x * inv, s1 = v0.y * inv, s2 = v0.z * inv, s3 = v0.w * inv;
  float s4 = v1.x * inv, s5 = v1.y * inv, s6 = v1.z * inv, s7 = v1.w * inv;
  uint4 p;
  p.x = f2bf(s0) | (f2bf(s1) << 16);
  p.y = f2bf(s2) | (f2bf(s3) << 16);
  p.z = f2bf(s4) | (f2bf(s5) << 16);
  p.w = f2bf(s6) | (f2bf(s7) << 16);
  zn[(size_t)row * (DD / 8) + lane] = p;
  if (side2) {
    float* d = z2s[w & 1] + lane * 8;
    d[0] = s0; d[1] = s1; d[2] = s2; d[3] = s3;
    d[4] = s4; d[5] = s5; d[6] = s6; d[7] = s7;
  }
  __syncthreads();
  if (!side2) {
    const float* q = z2s[w & 1] + lane * 8;
    float dv = s0 * q[0] + s1 * q[1] + s2 * q[2] + s3 * q[3] +
               s4 * q[4] + s5 * q[5] + s6 * q[6] + s7 * q[7];
#pragma unroll
    for (int o = 1; o < 64; o <<= 1) dv += __shfl_xor(dv, o, 64);
    if (lane == 0) tpart[jj] = 2.0f + 2.0f * dv;  // zn1.zn1 == 1 exactly; 1/T = 2
  }
}

// ---------- main: upper-triangular 256x256 tiles of S = zn.zn^T, 8-phase schedule ----------
__global__ __launch_bounds__(512, 2) void k_gemm_expsum(const unsigned short* __restrict__ zn,
                                                        float* __restrict__ rowsum) {
  __shared__ __align__(16) char smem[131072];  // [buf:2][op:2][32 KB]

  // XCD-chunked bijective swizzle (528 % 8 == 0) then triangular decode (bi <= bj)
  int tl = (blockIdx.x & 7) * (NTRI / 8) + (blockIdx.x >> 3);
  int bi = (int)((65.0f - sqrtf(4225.0f - 8.0f * (float)tl)) * 0.5f);
  if (bi < 0) bi = 0;
  if (bi > NBT - 1) bi = NBT - 1;
  while ((bi + 1) * NBT - ((bi + 1) * bi) / 2 <= tl) ++bi;
  while (bi * NBT - (bi * (bi - 1)) / 2 > tl) --bi;
  int bj = bi + (tl - (bi * NBT - (bi * (bi - 1)) / 2));

  const int tid = threadIdx.x;
  const int lane = tid & 63;
  const int wid = tid >> 6;
  const int wr = wid >> 2, wc = wid & 3;
  const int lr = lane & 15;
  const int kgrp = (lane >> 4) << 4;           // frag k-group byte
  const int kswz = (lane & 7) << 4;            // read-side XOR (row&7 == lane&7)

  const char* zb = (const char*)zn;
  const int arow0 = bi * 256, brow0 = bj * 256;
  const int srow = wid * 16 + (lane >> 3);     // stage row within a 128-row half
  const int cswz = (((lane & 7) ^ (lane >> 3)) << 4);  // pre-swizzled source col (rule #21)

#define STAGE_HALF(buf, op, h, rowbase, tau) do {                                        \
    char* _d = smem + (buf) * 65536 + (op) * 32768 + (h) * 16384 + wid * 2048;           \
    const char* _s = zb + (size_t)((rowbase) + (h) * 128 + srow) * 1024 + (tau) * 128 + cswz; \
    __builtin_amdgcn_global_load_lds((__attribute__((address_space(1))) void*)_s,        \
        (__attribute__((address_space(3))) void*)_d, 16, 0, 0);                          \
    __builtin_amdgcn_global_load_lds((__attribute__((address_space(1))) void*)(_s + 8 * 1024), \
        (__attribute__((address_space(3))) void*)(_d + 1024), 16, 0, 0);                 \
  } while (0)

  float4v acc[8][4];
#pragma unroll
  for (int m = 0; m < 8; ++m)
#pragma unroll
    for (int n = 0; n < 4; ++n) acc[m][n] = {0.f, 0.f, 0.f, 0.f};

  // prologue: A(0) h0,h1; B(0) h0,h1; A(1) h0,h1  -> 12 loads/thread
  STAGE_HALF(0, 0, 0, arow0, 0); STAGE_HALF(0, 0, 1, arow0, 0);
  STAGE_HALF(0, 1, 0, brow0, 0); STAGE_HALF(0, 1, 1, brow0, 0);
  STAGE_HALF(1, 0, 0, arow0, 1); STAGE_HALF(1, 0, 1, arow0, 1);
  asm volatile("s_waitcnt vmcnt(4)" ::: "memory");  // tile 0 (8 oldest) landed
  __builtin_amdgcn_s_barrier();

#pragma unroll
  for (int t = 0; t < NT; ++t) {
    const int c = t & 1, cn = c ^ 1;
    const char* ab = smem + c * 65536;
    const char* bb = ab + 32768;
    short8v a[2][4], b2[2][4];

    // ---- phase 0: read A-half0 frags + B n0..1; stage B(t+1).h0 ----
#pragma unroll
    for (int kk = 0; kk < 2; ++kk) {
#pragma unroll
      for (int mm = 0; mm < 4; ++mm)
        a[kk][mm] = *(const short8v*)(ab + (wr * 128 + mm * 16 + lr) * 128 + ((kk * 64 + kgrp) ^ kswz));
      b2[kk][0] = *(const short8v*)(bb + (wc * 64 + lr) * 128 + ((kk * 64 + kgrp) ^ kswz));
      b2[kk][1] = *(const short8v*)(bb + (wc * 64 + 16 + lr) * 128 + ((kk * 64 + kgrp) ^ kswz));
    }
    if (t + 1 < NT) STAGE_HALF(cn, 1, 0, brow0, t + 1);
    BAR();
    __builtin_amdgcn_s_setprio(1);
#pragma unroll
    for (int kk = 0; kk < 2; ++kk)
#pragma unroll
      for (int mm = 0; mm < 4; ++mm)
#pragma unroll
        for (int n = 0; n < 2; ++n)
          acc[mm][n] = __builtin_amdgcn_mfma_f32_16x16x32_bf16(a[kk][mm], b2[kk][n], acc[mm][n], 0, 0, 0);
    __builtin_amdgcn_s_setprio(0);
    BAR();

    // ---- phase 1: read B n2..3; stage B(t+1).h1 ----
#pragma unroll
    for (int kk = 0; kk < 2; ++kk) {
      b2[kk][2] = *(const short8v*)(bb + (wc * 64 + 32 + lr) * 128 + ((kk * 64 + kgrp) ^ kswz));
      b2[kk][3] = *(const short8v*)(bb + (wc * 64 + 48 + lr) * 128 + ((kk * 64 + kgrp) ^ kswz));
    }
    if (t + 1 < NT) STAGE_HALF(cn, 1, 1, brow0, t + 1);
    BAR();
    __builtin_amdgcn_s_setprio(1);
#pragma unroll
    for (int kk = 0; kk < 2; ++kk)
#pragma unroll
      for (int mm = 0; mm < 4; ++mm)
#pragma unroll
        for (int n = 0; n < 2; ++n)
          acc[mm][2 + n] = __builtin_amdgcn_mfma_f32_16x16x32_bf16(a[kk][mm], b2[kk][2 + n], acc[mm][2 + n], 0, 0, 0);
    __builtin_amdgcn_s_setprio(0);
    BAR();

    // ---- phase 2: read A-half1 frags ----
#pragma unroll
    for (int kk = 0; kk < 2; ++kk)
#pragma unroll
      for (int mm = 0; mm < 4; ++mm)
        a[kk][mm] = *(const short8v*)(ab + (wr * 128 + 64 + mm * 16 + lr) * 128 + ((kk * 64 + kgrp) ^ kswz));
    BAR();
    __builtin_amdgcn_s_setprio(1);
#pragma unroll
    for (int kk = 0; kk < 2; ++kk)
#pragma unroll
      for (int mm = 0; mm < 4; ++mm)
#pragma unroll
        for (int n = 0; n < 2; ++n)
          acc[4 + mm][2 + n] = __builtin_amdgcn_mfma_f32_16x16x32_bf16(a[kk][mm], b2[kk][2 + n], acc[4 + mm][2 + n], 0, 0, 0);
    __builtin_amdgcn_s_setprio(0);
    BAR();

    // ---- phase 3: stage A(t+2) into buf c (its reads finished at ph2); counted vmcnt ----
    if (t + 2 < NT) { STAGE_HALF(c, 0, 0, arow0, t + 2); STAGE_HALF(c, 0, 1, arow0, t + 2); }
    BAR();
    __builtin_amdgcn_s_setprio(1);
#pragma unroll
    for (int kk = 0; kk < 2; ++kk)
#pragma unroll
      for (int mm = 0; mm < 4; ++mm)
#pragma unroll
        for (int n = 0; n < 2; ++n)
          acc[4 + mm][n] = __builtin_amdgcn_mfma_f32_16x16x32_bf16(a[kk][mm], b2[kk][n], acc[4 + mm][n], 0, 0, 0);
    __builtin_amdgcn_s_setprio(0);
    if (t < NT - 2) asm volatile("s_waitcnt vmcnt(4)" ::: "memory");      // tile t+1 fully landed
    else if (t == NT - 2) asm volatile("s_waitcnt vmcnt(0)" ::: "memory"); // last tile: drain
    BAR();
  }
#undef STAGE_HALF

  // epilogue: e = exp(2*dot - 2) = exp2(C*dot - C)
  const float Cc = 2.88539008177792681f;
  float rowacc[8][4];
  float colacc[4] = {0.f, 0.f, 0.f, 0.f};
#pragma unroll
  for (int m = 0; m < 8; ++m)
#pragma unroll
    for (int r = 0; r < 4; ++r) rowacc[m][r] = 0.f;
#pragma unroll
  for (int m = 0; m < 8; ++m)
#pragma unroll
    for (int n = 0; n < 4; ++n)
#pragma unroll
      for (int r = 0; r < 4; ++r) {
        float e = exp2f(fmaf(acc[m][n][r], Cc, -Cc));
        rowacc[m][r] += e;
        colacc[n] += e;
      }

  // row sums: reduce over cols (lane&15); one atomic per row per wave
#pragma unroll
  for (int m = 0; m < 8; ++m)
#pragma unroll
    for (int r = 0; r < 4; ++r) {
      float v = rowacc[m][r];
      v += __shfl_xor(v, 1);
      v += __shfl_xor(v, 2);
      v += __shfl_xor(v, 4);
      v += __shfl_xor(v, 8);
      if ((lane & 15) == 0)
        atomicAdd(&rowsum[arow0 + wr * 128 + m * 16 + ((lane >> 4) << 2) + r], v);
    }
  // col sums (symmetric contribution), off-diagonal tiles only
  if (bi != bj) {
#pragma unroll
    for (int n = 0; n < 4; ++n) {
      float v = colacc[n];
      v += __shfl_xor(v, 16);
      v += __shfl_xor(v, 32);
      if (lane < 16) atomicAdd(&rowsum[brow0 + wc * 64 + n * 16 + lane], v);
    }
  }
}

// ---------- finalize: loss = (sum(2 + log rowsum) - sum tpart) / 8192 ----------
__global__ __launch_bounds__(256) void k_finalize(const float* __restrict__ rowsum,
                                                  const float* __restrict__ tpart,
                                                  float* __restrict__ out) {
  int t = threadIdx.x;
  float acc = 0.f;
  for (int i = t; i < N2; i += 256) acc += 2.0f + logf(rowsum[i]);
  for (int i = t; i < B_ROWS; i += 256) acc -= tpart[i];
#pragma unroll
  for (int off = 32; off; off >>= 1) acc += __shfl_down(acc, off, 64);
  __shared__ float wsum[4];
  if ((t & 63) == 0) wsum[t >> 6] = acc;
  __syncthreads();
  if (t == 0) out[0] = (wsum[0] + wsum[1] + wsum[2] + wsum[3]) * (1.0f / (float)N2);
}

extern "C" void kernel_launch(void* const* d_in, const int* in_sizes, int n_in,
                              void* d_out, int out_size, void* d_ws, size_t ws_size,
                              hipStream_t stream) {
  const float* f1 = (const float*)d_in[0];
  const float* f2 = (const float*)d_in[1];
  float* out = (float*)d_out;
  char* ws = (char*)d_ws;

  uint4* zn_w = (uint4*)ws;                                 // 8 MB bf16 zn
  unsigned short* zn = (unsigned short*)ws;
  float* rowsum = (float*)(ws + (size_t)N2 * DD * 2);       // 32 KB
  float* tpart = rowsum + N2;                               // 16 KB

  hipMemsetAsync(rowsum, 0, N2 * sizeof(float), stream);
  k_norm_tgt<<<B_ROWS / 2, 256, 0, stream>>>(f1, f2, zn_w, tpart);
  k_gemm_expsum<<<NTRI, 512, 0, stream>>>(zn, rowsum);
  k_finalize<<<1, 256, 0, stream>>>(rowsum, tpart, out);
}

// Round 4
// 116.840 us; speedup vs baseline: 1.0333x; 1.0333x over previous
//
#include <hip/hip_runtime.h>
#include <hip/hip_bf16.h>

#define B_ROWS 4096
#define N2 8192
#define DD 512
#define NB 64        // 8192/128 tile-blocks per dim
#define NTRI 2080    // NB*(NB+1)/2
#define NT 8         // DD/64 K-tiles

typedef __attribute__((ext_vector_type(8))) short short8v;
typedef __attribute__((ext_vector_type(4))) float float4v;

__device__ inline unsigned int f2bf(float f) {
  unsigned int u = __float_as_uint(f);
  u += 0x7fffu + ((u >> 16) & 1u);
  return u >> 16;
}

#define BAR() do { asm volatile("" ::: "memory"); __builtin_amdgcn_s_barrier(); asm volatile("" ::: "memory"); } while (0)

// ---------- normalize + targets + rowsum-zero, one wave per row-pair ----------
__global__ __launch_bounds__(256) void k_norm_tgt(const float* __restrict__ f1,
                                                  const float* __restrict__ f2,
                                                  uint4* __restrict__ zn,
                                                  float* __restrict__ tpart,
                                                  float* __restrict__ rowsum) {
  int w = threadIdx.x >> 6, lane = threadIdx.x & 63;
  int j = blockIdx.x * 4 + w;  // pair index 0..4095
  const float4* s1 = (const float4*)(f1 + (size_t)j * DD);
  const float4* s2 = (const float4*)(f2 + (size_t)j * DD);
  float4 a0 = s1[lane * 2], a1 = s1[lane * 2 + 1];
  float4 b0 = s2[lane * 2], b1 = s2[lane * 2 + 1];
  float ss1 = a0.x * a0.x + a0.y * a0.y + a0.z * a0.z + a0.w * a0.w +
              a1.x * a1.x + a1.y * a1.y + a1.z * a1.z + a1.w * a1.w;
  float ss2 = b0.x * b0.x + b0.y * b0.y + b0.z * b0.z + b0.w * b0.w +
              b1.x * b1.x + b1.y * b1.y + b1.z * b1.z + b1.w * b1.w;
  float ab = a0.x * b0.x + a0.y * b0.y + a0.z * b0.z + a0.w * b0.w +
             a1.x * b1.x + a1.y * b1.y + a1.z * b1.z + a1.w * b1.w;
#pragma unroll
  for (int o = 1; o < 64; o <<= 1) {
    ss1 += __shfl_xor(ss1, o, 64);
    ss2 += __shfl_xor(ss2, o, 64);
    ab += __shfl_xor(ab, o, 64);
  }
  float inv1 = 1.0f / fmaxf(sqrtf(ss1), 1e-8f);
  float inv2 = 1.0f / fmaxf(sqrtf(ss2), 1e-8f);
  uint4 p;
  p.x = f2bf(a0.x * inv1) | (f2bf(a0.y * inv1) << 16);
  p.y = f2bf(a0.z * inv1) | (f2bf(a0.w * inv1) << 16);
  p.z = f2bf(a1.x * inv1) | (f2bf(a1.y * inv1) << 16);
  p.w = f2bf(a1.z * inv1) | (f2bf(a1.w * inv1) << 16);
  zn[(size_t)j * (DD / 8) + lane] = p;
  p.x = f2bf(b0.x * inv2) | (f2bf(b0.y * inv2) << 16);
  p.y = f2bf(b0.z * inv2) | (f2bf(b0.w * inv2) << 16);
  p.z = f2bf(b1.x * inv2) | (f2bf(b1.y * inv2) << 16);
  p.w = f2bf(b1.z * inv2) | (f2bf(b1.w * inv2) << 16);
  zn[(size_t)(B_ROWS + j) * (DD / 8) + lane] = p;
  if (lane == 0) tpart[j] = 2.0f + 2.0f * ab * inv1 * inv2;  // logit[i,i] + logit[i,i+B]
  if (threadIdx.x < 8) rowsum[blockIdx.x * 8 + threadIdx.x] = 0.f;  // 1024*8 = 8192
}

// ---------- main: upper-triangular 128x128 tiles of S = zn.zn^T ----------
// Double-buffered LDS; STAGE(t+1) issued BEFORE compute(t); one vmcnt(0)+barrier/tile.
// rowsum[i] += sum_j exp(2*S_ij - 2); off-diag tiles also add col-sums (symmetry).
__global__ __launch_bounds__(256, 2) void k_gemm_expsum(const unsigned short* __restrict__ zn,
                                                        float* __restrict__ rowsum) {
  __shared__ __align__(16) char smem[65536];  // [buf:2][A 16KB | B 16KB]

  // XCD-chunked bijective swizzle (2080 % 8 == 0), then triangular decode (bi <= bj)
  int tl = (blockIdx.x & 7) * (NTRI / 8) + (blockIdx.x >> 3);
  int bi = (int)((129.0 - sqrt(16641.0 - 8.0 * (double)tl)) * 0.5);
  if (bi < 0) bi = 0;
  if (bi > NB - 1) bi = NB - 1;
  while ((bi + 1) * NB - ((bi + 1) * bi) / 2 <= tl) ++bi;
  while (bi * NB - (bi * (bi - 1)) / 2 > tl) --bi;
  int bj = bi + (tl - (bi * NB - (bi * (bi - 1)) / 2));

  const int tid = threadIdx.x;
  const int lane = tid & 63, w = tid >> 6;
  const int wr = w >> 1, wc = w & 1;
  const char* zb = (const char*)zn;
  const int arow0 = bi * 128, brow0 = bj * 128;

  // staging geometry (hoisted): 4 chunks/wave, 2 loads each (A,B)
  int sbase[4], scb[4], srow[4];
#pragma unroll
  for (int cc = 0; cc < 4; ++cc) {
    sbase[cc] = (w * 4 + cc) << 10;            // LDS byte base within a 16KB op-tile
    int lo = sbase[cc] + lane * 16;            // linear LDS dest = base + lane*16
    srow[cc] = lo >> 7;                        // tile row (128 B/row)
    scb[cc] = (lo & 127) ^ ((srow[cc] & 7) << 4);  // pre-swizzled SOURCE col (rule #21)
  }

#define STAGE(buf, tau) do {                                                             \
    char* _ab = smem + (buf) * 32768;                                                    \
    _Pragma("unroll")                                                                    \
    for (int cc = 0; cc < 4; ++cc) {                                                     \
      const char* _ga = zb + (size_t)(arow0 + srow[cc]) * 1024 + (tau) * 128 + scb[cc];  \
      const char* _gb = zb + (size_t)(brow0 + srow[cc]) * 1024 + (tau) * 128 + scb[cc];  \
      __builtin_amdgcn_global_load_lds((__attribute__((address_space(1))) void*)_ga,     \
          (__attribute__((address_space(3))) void*)(_ab + sbase[cc]), 16, 0, 0);         \
      __builtin_amdgcn_global_load_lds((__attribute__((address_space(1))) void*)_gb,     \
          (__attribute__((address_space(3))) void*)(_ab + 16384 + sbase[cc]), 16, 0, 0); \
    }                                                                                    \
  } while (0)

  float4v acc[4][4];
#pragma unroll
  for (int m = 0; m < 4; ++m)
#pragma unroll
    for (int n = 0; n < 4; ++n) acc[m][n] = {0.f, 0.f, 0.f, 0.f};

  // prologue: stage tile 0, drain, sync
  STAGE(0, 0);
  asm volatile("s_waitcnt vmcnt(0)" ::: "memory");
  __builtin_amdgcn_s_barrier();

#pragma unroll
  for (int t = 0; t < NT; ++t) {
    const int c = t & 1;
    if (t + 1 < NT) STAGE(c ^ 1, t + 1);  // prefetch next tile first (latency hides under compute)
    const char* ab = smem + c * 32768;
    const char* bb = ab + 16384;
#pragma unroll
    for (int kk = 0; kk < 2; ++kk) {
      short8v a[4], b[4];
      int koff = kk * 64 + ((lane >> 4) << 4);
#pragma unroll
      for (int m = 0; m < 4; ++m) {
        int row = wr * 64 + m * 16 + (lane & 15);
        a[m] = *(const short8v*)(ab + row * 128 + (koff ^ ((row & 7) << 4)));
      }
#pragma unroll
      for (int n = 0; n < 4; ++n) {
        int row = wc * 64 + n * 16 + (lane & 15);
        b[n] = *(const short8v*)(bb + row * 128 + (koff ^ ((row & 7) << 4)));
      }
#pragma unroll
      for (int m = 0; m < 4; ++m)
#pragma unroll
        for (int n = 0; n < 4; ++n)
          acc[m][n] = __builtin_amdgcn_mfma_f32_16x16x32_bf16(a[m], b[n], acc[m][n], 0, 0, 0);
    }
    if (t + 1 < NT) asm volatile("s_waitcnt vmcnt(0)" ::: "memory");  // t+1 landed
    BAR();
  }
#undef STAGE

  // epilogue: e = exp(2*dot - 2) = exp2(C*dot - C)
  const float C = 2.88539008177792681f;
  float rowacc[4][4];
  float colacc[4] = {0.f, 0.f, 0.f, 0.f};
#pragma unroll
  for (int m = 0; m < 4; ++m)
#pragma unroll
    for (int r = 0; r < 4; ++r) rowacc[m][r] = 0.f;
#pragma unroll
  for (int m = 0; m < 4; ++m)
#pragma unroll
    for (int n = 0; n < 4; ++n)
#pragma unroll
      for (int r = 0; r < 4; ++r) {
        float e = exp2f(fmaf(acc[m][n][r], C, -C));
        rowacc[m][r] += e;
        colacc[n] += e;
      }

  // row sums: reduce over columns (lane&15); one atomic per row per wave
#pragma unroll
  for (int m = 0; m < 4; ++m)
#pragma unroll
    for (int r = 0; r < 4; ++r) {
      float v = rowacc[m][r];
      v += __shfl_xor(v, 1);
      v += __shfl_xor(v, 2);
      v += __shfl_xor(v, 4);
      v += __shfl_xor(v, 8);
      if ((lane & 15) == 0)
        atomicAdd(&rowsum[arow0 + wr * 64 + m * 16 + ((lane >> 4) << 2) + r], v);
    }
  // col sums (symmetric contribution), off-diagonal tiles only
  if (bi != bj) {
#pragma unroll
    for (int n = 0; n < 4; ++n) {
      float v = colacc[n];
      v += __shfl_xor(v, 16);
      v += __shfl_xor(v, 32);
      if (lane < 16) atomicAdd(&rowsum[brow0 + wc * 64 + n * 16 + lane], v);
    }
  }
}

// ---------- finalize: loss = (sum(2 + log rowsum) - sum tpart) / 8192 ----------
__global__ __launch_bounds__(256) void k_finalize(const float* __restrict__ rowsum,
                                                  const float* __restrict__ tpart,
                                                  float* __restrict__ out) {
  int t = threadIdx.x;
  float acc = 0.f;
  for (int i = t; i < N2; i += 256) acc += 2.0f + logf(rowsum[i]);
  for (int i = t; i < B_ROWS; i += 256) acc -= tpart[i];
#pragma unroll
  for (int off = 32; off; off >>= 1) acc += __shfl_down(acc, off, 64);
  __shared__ float wsum[4];
  if ((t & 63) == 0) wsum[t >> 6] = acc;
  __syncthreads();
  if (t == 0) out[0] = (wsum[0] + wsum[1] + wsum[2] + wsum[3]) * (1.0f / (float)N2);
}

extern "C" void kernel_launch(void* const* d_in, const int* in_sizes, int n_in,
                              void* d_out, int out_size, void* d_ws, size_t ws_size,
                              hipStream_t stream) {
  const float* f1 = (const float*)d_in[0];
  const float* f2 = (const float*)d_in[1];
  float* out = (float*)d_out;
  char* ws = (char*)d_ws;

  uint4* zn_w = (uint4*)ws;                              // 8 MB bf16 zn
  unsigned short* zn = (unsigned short*)ws;
  float* rowsum = (float*)(ws + (size_t)N2 * DD * 2);    // 32 KB
  float* tpart = rowsum + N2;                            // 16 KB

  k_norm_tgt<<<B_ROWS / 4, 256, 0, stream>>>(f1, f2, zn_w, tpart, rowsum);
  k_gemm_expsum<<<NTRI, 256, 0, stream>>>(zn, rowsum);
  k_finalize<<<1, 256, 0, stream>>>(rowsum, tpart, out);
}

// Round 5
// 116.783 us; speedup vs baseline: 1.0338x; 1.0005x over previous
//
#include <hip/hip_runtime.h>
#include <hip/hip_bf16.h>

#define B_ROWS 4096
#define N2 8192
#define DD 512
#define NB 64        // 8192/128 tile-blocks per dim
#define NTRI 2080    // NB*(NB+1)/2
#define NT 8         // DD/64 K-tiles

typedef __attribute__((ext_vector_type(8))) short short8v;
typedef __attribute__((ext_vector_type(4))) float float4v;

__device__ inline unsigned int f2bf(float f) {
  unsigned int u = __float_as_uint(f);
  u += 0x7fffu + ((u >> 16) & 1u);
  return u >> 16;
}

#define BAR() do { asm volatile("" ::: "memory"); __builtin_amdgcn_s_barrier(); asm volatile("" ::: "memory"); } while (0)

// ---------- normalize + targets + rowsum-zero, one wave per row-pair ----------
__global__ __launch_bounds__(256) void k_norm_tgt(const float* __restrict__ f1,
                                                  const float* __restrict__ f2,
                                                  uint4* __restrict__ zn,
                                                  float* __restrict__ tpart,
                                                  float* __restrict__ rowsum) {
  int w = threadIdx.x >> 6, lane = threadIdx.x & 63;
  int j = blockIdx.x * 4 + w;  // pair index 0..4095
  const float4* s1 = (const float4*)(f1 + (size_t)j * DD);
  const float4* s2 = (const float4*)(f2 + (size_t)j * DD);
  float4 a0 = s1[lane * 2], a1 = s1[lane * 2 + 1];
  float4 b0 = s2[lane * 2], b1 = s2[lane * 2 + 1];
  float ss1 = a0.x * a0.x + a0.y * a0.y + a0.z * a0.z + a0.w * a0.w +
              a1.x * a1.x + a1.y * a1.y + a1.z * a1.z + a1.w * a1.w;
  float ss2 = b0.x * b0.x + b0.y * b0.y + b0.z * b0.z + b0.w * b0.w +
              b1.x * b1.x + b1.y * b1.y + b1.z * b1.z + b1.w * b1.w;
  float ab = a0.x * b0.x + a0.y * b0.y + a0.z * b0.z + a0.w * b0.w +
             a1.x * b1.x + a1.y * b1.y + a1.z * b1.z + a1.w * b1.w;
#pragma unroll
  for (int o = 1; o < 64; o <<= 1) {
    ss1 += __shfl_xor(ss1, o, 64);
    ss2 += __shfl_xor(ss2, o, 64);
    ab += __shfl_xor(ab, o, 64);
  }
  float inv1 = 1.0f / fmaxf(sqrtf(ss1), 1e-8f);
  float inv2 = 1.0f / fmaxf(sqrtf(ss2), 1e-8f);
  uint4 p;
  p.x = f2bf(a0.x * inv1) | (f2bf(a0.y * inv1) << 16);
  p.y = f2bf(a0.z * inv1) | (f2bf(a0.w * inv1) << 16);
  p.z = f2bf(a1.x * inv1) | (f2bf(a1.y * inv1) << 16);
  p.w = f2bf(a1.z * inv1) | (f2bf(a1.w * inv1) << 16);
  zn[(size_t)j * (DD / 8) + lane] = p;
  p.x = f2bf(b0.x * inv2) | (f2bf(b0.y * inv2) << 16);
  p.y = f2bf(b0.z * inv2) | (f2bf(b0.w * inv2) << 16);
  p.z = f2bf(b1.x * inv2) | (f2bf(b1.y * inv2) << 16);
  p.w = f2bf(b1.z * inv2) | (f2bf(b1.w * inv2) << 16);
  zn[(size_t)(B_ROWS + j) * (DD / 8) + lane] = p;
  if (lane == 0) tpart[j] = 2.0f + 2.0f * ab * inv1 * inv2;  // logit[i,i] + logit[i,i+B]
  if (threadIdx.x < 8) rowsum[blockIdx.x * 8 + threadIdx.x] = 0.f;  // 1024*8 = 8192
}

// ---------- main: upper-triangular 128x128 tiles of S = zn.zn^T ----------
// Double-buffered LDS; STAGE(t+1) issued BEFORE compute(t); one vmcnt(0)+barrier/tile.
// rowsum[i] += sum_j exp(2*S_ij - 2); off-diag tiles also add col-sums (symmetry).
__global__ __launch_bounds__(256, 2) void k_gemm_expsum(const unsigned short* __restrict__ zn,
                                                        float* __restrict__ rowsum) {
  __shared__ __align__(16) char smem[65536];  // [buf:2][A 16KB | B 16KB]

  // XCD-chunked bijective swizzle (2080 % 8 == 0), then triangular decode (bi <= bj)
  int tl = (blockIdx.x & 7) * (NTRI / 8) + (blockIdx.x >> 3);
  int bi = (int)((129.0 - sqrt(16641.0 - 8.0 * (double)tl)) * 0.5);
  if (bi < 0) bi = 0;
  if (bi > NB - 1) bi = NB - 1;
  while ((bi + 1) * NB - ((bi + 1) * bi) / 2 <= tl) ++bi;
  while (bi * NB - (bi * (bi - 1)) / 2 > tl) --bi;
  int bj = bi + (tl - (bi * NB - (bi * (bi - 1)) / 2));

  const int tid = threadIdx.x;
  const int lane = tid & 63, w = tid >> 6;
  const int wr = w >> 1, wc = w & 1;
  const char* zb = (const char*)zn;
  const int arow0 = bi * 128, brow0 = bj * 128;

  // staging geometry (hoisted): 4 chunks/wave, 2 loads each (A,B)
  int sbase[4], scb[4], srow[4];
#pragma unroll
  for (int cc = 0; cc < 4; ++cc) {
    sbase[cc] = (w * 4 + cc) << 10;            // LDS byte base within a 16KB op-tile
    int lo = sbase[cc] + lane * 16;            // linear LDS dest = base + lane*16
    srow[cc] = lo >> 7;                        // tile row (128 B/row)
    scb[cc] = (lo & 127) ^ ((srow[cc] & 7) << 4);  // pre-swizzled SOURCE col (rule #21)
  }

#define STAGE(buf, tau) do {                                                             \
    char* _ab = smem + (buf) * 32768;                                                    \
    _Pragma("unroll")                                                                    \
    for (int cc = 0; cc < 4; ++cc) {                                                     \
      const char* _ga = zb + (size_t)(arow0 + srow[cc]) * 1024 + (tau) * 128 + scb[cc];  \
      const char* _gb = zb + (size_t)(brow0 + srow[cc]) * 1024 + (tau) * 128 + scb[cc];  \
      __builtin_amdgcn_global_load_lds((__attribute__((address_space(1))) void*)_ga,     \
          (__attribute__((address_space(3))) void*)(_ab + sbase[cc]), 16, 0, 0);         \
      __builtin_amdgcn_global_load_lds((__attribute__((address_space(1))) void*)_gb,     \
          (__attribute__((address_space(3))) void*)(_ab + 16384 + sbase[cc]), 16, 0, 0); \
    }                                                                                    \
  } while (0)

  float4v acc[4][4];
#pragma unroll
  for (int m = 0; m < 4; ++m)
#pragma unroll
    for (int n = 0; n < 4; ++n) acc[m][n] = {0.f, 0.f, 0.f, 0.f};

  // prologue: stage tile 0, drain, sync
  STAGE(0, 0);
  asm volatile("s_waitcnt vmcnt(0)" ::: "memory");
  __builtin_amdgcn_s_barrier();

#pragma unroll
  for (int t = 0; t < NT; ++t) {
    const int c = t & 1;
    if (t + 1 < NT) STAGE(c ^ 1, t + 1);  // prefetch next tile first (latency hides under compute)
    const char* ab = smem + c * 32768;
    const char* bb = ab + 16384;
#pragma unroll
    for (int kk = 0; kk < 2; ++kk) {
      short8v a[4], b[4];
      int koff = kk * 64 + ((lane >> 4) << 4);
#pragma unroll
      for (int m = 0; m < 4; ++m) {
        int row = wr * 64 + m * 16 + (lane & 15);
        a[m] = *(const short8v*)(ab + row * 128 + (koff ^ ((row & 7) << 4)));
      }
#pragma unroll
      for (int n = 0; n < 4; ++n) {
        int row = wc * 64 + n * 16 + (lane & 15);
        b[n] = *(const short8v*)(bb + row * 128 + (koff ^ ((row & 7) << 4)));
      }
#pragma unroll
      for (int m = 0; m < 4; ++m)
#pragma unroll
        for (int n = 0; n < 4; ++n)
          acc[m][n] = __builtin_amdgcn_mfma_f32_16x16x32_bf16(a[m], b[n], acc[m][n], 0, 0, 0);
    }
    if (t + 1 < NT) asm volatile("s_waitcnt vmcnt(0)" ::: "memory");  // t+1 landed
    BAR();
  }
#undef STAGE

  // epilogue: e = exp(2*dot - 2) = exp2(C*dot - C)
  const float C = 2.88539008177792681f;
  float rowacc[4][4];
  float colacc[4] = {0.f, 0.f, 0.f, 0.f};
#pragma unroll
  for (int m = 0; m < 4; ++m)
#pragma unroll
    for (int r = 0; r < 4; ++r) rowacc[m][r] = 0.f;
#pragma unroll
  for (int m = 0; m < 4; ++m)
#pragma unroll
    for (int n = 0; n < 4; ++n)
#pragma unroll
      for (int r = 0; r < 4; ++r) {
        float e = exp2f(fmaf(acc[m][n][r], C, -C));
        rowacc[m][r] += e;
        colacc[n] += e;
      }

  // row sums: reduce over columns (lane&15); one atomic per row per wave
#pragma unroll
  for (int m = 0; m < 4; ++m)
#pragma unroll
    for (int r = 0; r < 4; ++r) {
      float v = rowacc[m][r];
      v += __shfl_xor(v, 1);
      v += __shfl_xor(v, 2);
      v += __shfl_xor(v, 4);
      v += __shfl_xor(v, 8);
      if ((lane & 15) == 0)
        atomicAdd(&rowsum[arow0 + wr * 64 + m * 16 + ((lane >> 4) << 2) + r], v);
    }
  // col sums (symmetric contribution), off-diagonal tiles only
  if (bi != bj) {
#pragma unroll
    for (int n = 0; n < 4; ++n) {
      float v = colacc[n];
      v += __shfl_xor(v, 16);
      v += __shfl_xor(v, 32);
      if (lane < 16) atomicAdd(&rowsum[brow0 + wc * 64 + n * 16 + lane], v);
    }
  }
}

// ---------- finalize: loss = (sum(2 + log rowsum) - sum tpart) / 8192 ----------
__global__ __launch_bounds__(256) void k_finalize(const float* __restrict__ rowsum,
                                                  const float* __restrict__ tpart,
                                                  float* __restrict__ out) {
  int t = threadIdx.x;
  float acc = 0.f;
  for (int i = t; i < N2; i += 256) acc += 2.0f + logf(rowsum[i]);
  for (int i = t; i < B_ROWS; i += 256) acc -= tpart[i];
#pragma unroll
  for (int off = 32; off; off >>= 1) acc += __shfl_down(acc, off, 64);
  __shared__ float wsum[4];
  if ((t & 63) == 0) wsum[t >> 6] = acc;
  __syncthreads();
  if (t == 0) out[0] = (wsum[0] + wsum[1] + wsum[2] + wsum[3]) * (1.0f / (float)N2);
}

extern "C" void kernel_launch(void* const* d_in, const int* in_sizes, int n_in,
                              void* d_out, int out_size, void* d_ws, size_t ws_size,
                              hipStream_t stream) {
  const float* f1 = (const float*)d_in[0];
  const float* f2 = (const float*)d_in[1];
  float* out = (float*)d_out;
  char* ws = (char*)d_ws;

  uint4* zn_w = (uint4*)ws;                              // 8 MB bf16 zn
  unsigned short* zn = (unsigned short*)ws;
  float* rowsum = (float*)(ws + (size_t)N2 * DD * 2);    // 32 KB
  float* tpart = rowsum + N2;                            // 16 KB

  k_norm_tgt<<<B_ROWS / 4, 256, 0, stream>>>(f1, f2, zn_w, tpart, rowsum);
  k_gemm_expsum<<<NTRI, 256, 0, stream>>>(zn, rowsum);
  k_finalize<<<1, 256, 0, stream>>>(rowsum, tpart, out);
}

// Round 6
// 87.140 us; speedup vs baseline: 1.3855x; 1.3402x over previous
//
#include <hip/hip_runtime.h>
#include <hip/hip_bf16.h>

#define B_ROWS 4096
#define N2 8192
#define DD 512
#define NB 64        // 8192/128 tile-blocks per dim
#define NTRI 2080    // NB*(NB+1)/2
#define NT 8         // DD/64 K-tiles

typedef __attribute__((ext_vector_type(8))) short short8v;
typedef __attribute__((ext_vector_type(4))) float float4v;

__device__ inline unsigned int f2bf(float f) {
  unsigned int u = __float_as_uint(f);
  u += 0x7fffu + ((u >> 16) & 1u);
  return u >> 16;
}

#define BAR() do { asm volatile("" ::: "memory"); __builtin_amdgcn_s_barrier(); asm volatile("" ::: "memory"); } while (0)

// ---------- normalize + targets + rowsum-zero, one wave per row-pair ----------
__global__ __launch_bounds__(256) void k_norm_tgt(const float* __restrict__ f1,
                                                  const float* __restrict__ f2,
                                                  uint4* __restrict__ zn,
                                                  float* __restrict__ tpart,
                                                  float* __restrict__ rowsum) {
  int w = threadIdx.x >> 6, lane = threadIdx.x & 63;
  int j = blockIdx.x * 4 + w;  // pair index 0..4095
  const float4* s1 = (const float4*)(f1 + (size_t)j * DD);
  const float4* s2 = (const float4*)(f2 + (size_t)j * DD);
  float4 a0 = s1[lane * 2], a1 = s1[lane * 2 + 1];
  float4 b0 = s2[lane * 2], b1 = s2[lane * 2 + 1];
  float ss1 = a0.x * a0.x + a0.y * a0.y + a0.z * a0.z + a0.w * a0.w +
              a1.x * a1.x + a1.y * a1.y + a1.z * a1.z + a1.w * a1.w;
  float ss2 = b0.x * b0.x + b0.y * b0.y + b0.z * b0.z + b0.w * b0.w +
              b1.x * b1.x + b1.y * b1.y + b1.z * b1.z + b1.w * b1.w;
  float ab = a0.x * b0.x + a0.y * b0.y + a0.z * b0.z + a0.w * b0.w +
             a1.x * b1.x + a1.y * b1.y + a1.z * b1.z + a1.w * b1.w;
#pragma unroll
  for (int o = 1; o < 64; o <<= 1) {
    ss1 += __shfl_xor(ss1, o, 64);
    ss2 += __shfl_xor(ss2, o, 64);
    ab += __shfl_xor(ab, o, 64);
  }
  float inv1 = 1.0f / fmaxf(sqrtf(ss1), 1e-8f);
  float inv2 = 1.0f / fmaxf(sqrtf(ss2), 1e-8f);
  uint4 p;
  p.x = f2bf(a0.x * inv1) | (f2bf(a0.y * inv1) << 16);
  p.y = f2bf(a0.z * inv1) | (f2bf(a0.w * inv1) << 16);
  p.z = f2bf(a1.x * inv1) | (f2bf(a1.y * inv1) << 16);
  p.w = f2bf(a1.z * inv1) | (f2bf(a1.w * inv1) << 16);
  zn[(size_t)j * (DD / 8) + lane] = p;
  p.x = f2bf(b0.x * inv2) | (f2bf(b0.y * inv2) << 16);
  p.y = f2bf(b0.z * inv2) | (f2bf(b0.w * inv2) << 16);
  p.z = f2bf(b1.x * inv2) | (f2bf(b1.y * inv2) << 16);
  p.w = f2bf(b1.z * inv2) | (f2bf(b1.w * inv2) << 16);
  zn[(size_t)(B_ROWS + j) * (DD / 8) + lane] = p;
  if (lane == 0) tpart[j] = 2.0f + 2.0f * ab * inv1 * inv2;  // logit[i,i] + logit[i,i+B]
  if (threadIdx.x < 8) rowsum[blockIdx.x * 8 + threadIdx.x] = 0.f;  // 1024*8 = 8192
}

// ---------- main: upper-triangular 128x128 tiles of S = zn.zn^T ----------
// Band-major tile order (bands of 8 bj-panels = 1MB, L2-resident per XCD) +
// XCD-chunked swizzle. Double-buffered LDS; STAGE(t+1) before compute(t).
__global__ __launch_bounds__(256, 2) void k_gemm_expsum(const unsigned short* __restrict__ zn,
                                                        float* __restrict__ rowsum) {
  __shared__ __align__(16) char smem[65536];  // [buf:2][A 16KB | B 16KB]

  // XCD-chunked swizzle (2080 % 8 == 0): each XCD gets a contiguous band-major range
  int g = (blockIdx.x & 7) * (NTRI / 8) + (blockIdx.x >> 3);

  // band-major decode: band b covers bj in [8b, 8b+8), bi in [0, bj].
  // off(b) = 32*b*b + 4*b; full-rows part (bi < 8b) is bi-major, then 8x8 upper-tri.
  int b = 7;
  while (32 * b * b + 4 * b > g) --b;
  int tp = g - (32 * b * b + 4 * b);
  int bi, bj;
  if (tp < 64 * b) {
    bi = tp >> 3;                 // A panel reused for 8 consecutive tiles
    bj = 8 * b + (tp & 7);        // B window: 8 panels, hot in L2
  } else {
    int u = tp - 64 * b;          // 0..35: upper-tri of the 8x8 diagonal block
    int r = 0;
    while ((r + 1) * 8 - (r * (r + 1)) / 2 <= u) ++r;
    int before = r * 8 - ((r - 1) * r) / 2;
    bi = 8 * b + r;
    bj = 8 * b + r + (u - before);
  }

  const int tid = threadIdx.x;
  const int lane = tid & 63, w = tid >> 6;
  const int wr = w >> 1, wc = w & 1;
  const char* zb = (const char*)zn;
  const int arow0 = bi * 128, brow0 = bj * 128;

  // staging geometry (hoisted): 4 chunks/wave, 2 loads each (A,B)
  int sbase[4], scb[4], srow[4];
#pragma unroll
  for (int cc = 0; cc < 4; ++cc) {
    sbase[cc] = (w * 4 + cc) << 10;            // LDS byte base within a 16KB op-tile
    int lo = sbase[cc] + lane * 16;            // linear LDS dest = base + lane*16
    srow[cc] = lo >> 7;                        // tile row (128 B/row)
    scb[cc] = (lo & 127) ^ ((srow[cc] & 7) << 4);  // pre-swizzled SOURCE col (rule #21)
  }

#define STAGE(buf, tau) do {                                                             \
    char* _ab = smem + (buf) * 32768;                                                    \
    _Pragma("unroll")                                                                    \
    for (int cc = 0; cc < 4; ++cc) {                                                     \
      const char* _ga = zb + (size_t)(arow0 + srow[cc]) * 1024 + (tau) * 128 + scb[cc];  \
      const char* _gb = zb + (size_t)(brow0 + srow[cc]) * 1024 + (tau) * 128 + scb[cc];  \
      __builtin_amdgcn_global_load_lds((__attribute__((address_space(1))) void*)_ga,     \
          (__attribute__((address_space(3))) void*)(_ab + sbase[cc]), 16, 0, 0);         \
      __builtin_amdgcn_global_load_lds((__attribute__((address_space(1))) void*)_gb,     \
          (__attribute__((address_space(3))) void*)(_ab + 16384 + sbase[cc]), 16, 0, 0); \
    }                                                                                    \
  } while (0)

  float4v acc[4][4];
#pragma unroll
  for (int m = 0; m < 4; ++m)
#pragma unroll
    for (int n = 0; n < 4; ++n) acc[m][n] = {0.f, 0.f, 0.f, 0.f};

  // prologue: stage tile 0, drain, sync
  STAGE(0, 0);
  asm volatile("s_waitcnt vmcnt(0)" ::: "memory");
  __builtin_amdgcn_s_barrier();

#pragma unroll
  for (int t = 0; t < NT; ++t) {
    const int c = t & 1;
    if (t + 1 < NT) STAGE(c ^ 1, t + 1);  // prefetch next tile first (hides under compute)
    const char* ab = smem + c * 32768;
    const char* bb = ab + 16384;
#pragma unroll
    for (int kk = 0; kk < 2; ++kk) {
      short8v a[4], bf[4];
      int koff = kk * 64 + ((lane >> 4) << 4);
#pragma unroll
      for (int m = 0; m < 4; ++m) {
        int row = wr * 64 + m * 16 + (lane & 15);
        a[m] = *(const short8v*)(ab + row * 128 + (koff ^ ((row & 7) << 4)));
      }
#pragma unroll
      for (int n = 0; n < 4; ++n) {
        int row = wc * 64 + n * 16 + (lane & 15);
        bf[n] = *(const short8v*)(bb + row * 128 + (koff ^ ((row & 7) << 4)));
      }
#pragma unroll
      for (int m = 0; m < 4; ++m)
#pragma unroll
        for (int n = 0; n < 4; ++n)
          acc[m][n] = __builtin_amdgcn_mfma_f32_16x16x32_bf16(a[m], bf[n], acc[m][n], 0, 0, 0);
    }
    if (t + 1 < NT) asm volatile("s_waitcnt vmcnt(0)" ::: "memory");  // t+1 landed
    BAR();
  }
#undef STAGE

  // epilogue: e = exp(2*dot - 2) = exp2(C*dot - C)
  const float C = 2.88539008177792681f;
  float rowacc[4][4];
  float colacc[4] = {0.f, 0.f, 0.f, 0.f};
#pragma unroll
  for (int m = 0; m < 4; ++m)
#pragma unroll
    for (int r = 0; r < 4; ++r) rowacc[m][r] = 0.f;
#pragma unroll
  for (int m = 0; m < 4; ++m)
#pragma unroll
    for (int n = 0; n < 4; ++n)
#pragma unroll
      for (int r = 0; r < 4; ++r) {
        float e = exp2f(fmaf(acc[m][n][r], C, -C));
        rowacc[m][r] += e;
        colacc[n] += e;
      }

  // row sums: reduce over columns (lane&15); one atomic per row per wave
#pragma unroll
  for (int m = 0; m < 4; ++m)
#pragma unroll
    for (int r = 0; r < 4; ++r) {
      float v = rowacc[m][r];
      v += __shfl_xor(v, 1);
      v += __shfl_xor(v, 2);
      v += __shfl_xor(v, 4);
      v += __shfl_xor(v, 8);
      if ((lane & 15) == 0)
        atomicAdd(&rowsum[arow0 + wr * 64 + m * 16 + ((lane >> 4) << 2) + r], v);
    }
  // col sums (symmetric contribution), off-diagonal tiles only
  if (bi != bj) {
#pragma unroll
    for (int n = 0; n < 4; ++n) {
      float v = colacc[n];
      v += __shfl_xor(v, 16);
      v += __shfl_xor(v, 32);
      if (lane < 16) atomicAdd(&rowsum[brow0 + wc * 64 + n * 16 + lane], v);
    }
  }
}

// ---------- finalize: loss = (sum(2 + log rowsum) - sum tpart) / 8192 ----------
__global__ __launch_bounds__(256) void k_finalize(const float* __restrict__ rowsum,
                                                  const float* __restrict__ tpart,
                                                  float* __restrict__ out) {
  int t = threadIdx.x;
  float acc = 0.f;
  for (int i = t; i < N2; i += 256) acc += 2.0f + logf(rowsum[i]);
  for (int i = t; i < B_ROWS; i += 256) acc -= tpart[i];
#pragma unroll
  for (int off = 32; off; off >>= 1) acc += __shfl_down(acc, off, 64);
  __shared__ float wsum[4];
  if ((t & 63) == 0) wsum[t >> 6] = acc;
  __syncthreads();
  if (t == 0) out[0] = (wsum[0] + wsum[1] + wsum[2] + wsum[3]) * (1.0f / (float)N2);
}

extern "C" void kernel_launch(void* const* d_in, const int* in_sizes, int n_in,
                              void* d_out, int out_size, void* d_ws, size_t ws_size,
                              hipStream_t stream) {
  const float* f1 = (const float*)d_in[0];
  const float* f2 = (const float*)d_in[1];
  float* out = (float*)d_out;
  char* ws = (char*)d_ws;

  uint4* zn_w = (uint4*)ws;                              // 8 MB bf16 zn
  unsigned short* zn = (unsigned short*)ws;
  float* rowsum = (float*)(ws + (size_t)N2 * DD * 2);    // 32 KB
  float* tpart = rowsum + N2;                            // 16 KB

  k_norm_tgt<<<B_ROWS / 4, 256, 0, stream>>>(f1, f2, zn_w, tpart, rowsum);
  k_gemm_expsum<<<NTRI, 256, 0, stream>>>(zn, rowsum);
  k_finalize<<<1, 256, 0, stream>>>(rowsum, tpart, out);
}